// Round 1
// baseline (217.512 us; speedup 1.0000x reference)
//
#include <hip/hip_runtime.h>
#include <cstdint>

// Problem constants (fixed by the reference):
//   B=16384 rows, K=2048 centers, D=128, T=1.0
// Outputs (flat, float32): out[B*D], center[K*D], label[B]
#define NB 16384
#define NK 2048
#define ND 128

// ---------------------------------------------------------------------------
// Prep 1: transpose center [K][D] -> cT [D][K]  (coalesced writes)
// ---------------------------------------------------------------------------
__global__ void transpose_center(const float* __restrict__ c,
                                 float* __restrict__ cT) {
    int t = blockIdx.x * blockDim.x + threadIdx.x;   // 0 .. K*D-1
    int d = t >> 11;          // / 2048
    int k = t & (NK - 1);
    cT[t] = c[k * ND + d];
}

// ---------------------------------------------------------------------------
// Prep 2: c2[k] = sum_d center[k][d]^2
// ---------------------------------------------------------------------------
__global__ void compute_c2(const float* __restrict__ c, float* __restrict__ c2) {
    int k = blockIdx.x * blockDim.x + threadIdx.x;
    const float4* row = (const float4*)(c + (long)k * ND);
    float s = 0.f;
#pragma unroll 8
    for (int i = 0; i < ND / 4; ++i) {
        float4 v = row[i];
        s += v.x * v.x + v.y * v.y + v.z * v.z + v.w * v.w;
    }
    c2[k] = s;
}

// ---------------------------------------------------------------------------
// Prep 3: x2[b] = sum_d x[b][d]^2   (one wave per row)
// ---------------------------------------------------------------------------
__global__ void compute_x2(const float* __restrict__ x, float* __restrict__ x2) {
    int wave = (blockIdx.x * blockDim.x + threadIdx.x) >> 6;
    int lane = threadIdx.x & 63;
    float2 v = ((const float2*)(x + (long)wave * ND))[lane];
    float s = v.x * v.x + v.y * v.y;
#pragma unroll
    for (int off = 32; off; off >>= 1) s += __shfl_xor(s, off, 64);
    if (lane == 0) x2[wave] = s;
}

// ---------------------------------------------------------------------------
// Main: per-row argmin of s_k = sqrt(max((x2+c2_k) - 2*dot,0)), tie -> low k.
// Wave handles 8 rows; lane handles 4 consecutive k per 256-k chunk.
// 32 fp32 accumulators/lane; center read via coalesced float4 from cT;
// x read via wave-uniform scalar loads.
// ---------------------------------------------------------------------------
__global__ __launch_bounds__(256)
void kmeans_main(const float* __restrict__ x,
                 const float* __restrict__ center,
                 const float* __restrict__ cT,
                 const float* __restrict__ c2,
                 const float* __restrict__ x2,
                 float* __restrict__ out,
                 float* __restrict__ label_out) {
    const int lane = threadIdx.x & 63;
    const int wave = __builtin_amdgcn_readfirstlane(threadIdx.x >> 6);
    const long row_base = ((long)blockIdx.x * 4 + wave) * 8;
    const float* __restrict__ xr = x + row_base * ND;   // wave-uniform base

    float x2v[8];
#pragma unroll
    for (int r = 0; r < 8; ++r) x2v[r] = x2[row_base + r];  // uniform -> s_load

    unsigned long long best[8];
#pragma unroll
    for (int r = 0; r < 8; ++r) best[r] = ~0ULL;

    for (int chunk = 0; chunk < 8; ++chunk) {
        const int kk = chunk * 256 + lane * 4;           // this lane's 4 k's
        float acc[8][4];
#pragma unroll
        for (int r = 0; r < 8; ++r)
#pragma unroll
            for (int j = 0; j < 4; ++j) acc[r][j] = 0.f;

        const float4* cptr = (const float4*)(cT + kk);   // row stride 512 f4
#pragma unroll 4
        for (int d = 0; d < ND; ++d) {
            float4 c4 = cptr[d * (NK / 4)];
#pragma unroll
            for (int r = 0; r < 8; ++r) {
                float xv = xr[r * ND + d];               // uniform -> s_load
                acc[r][0] = fmaf(xv, c4.x, acc[r][0]);
                acc[r][1] = fmaf(xv, c4.y, acc[r][1]);
                acc[r][2] = fmaf(xv, c4.z, acc[r][2]);
                acc[r][3] = fmaf(xv, c4.w, acc[r][3]);
            }
        }

        float4 c2v = *(const float4*)(c2 + kk);
        float c2a[4] = {c2v.x, c2v.y, c2v.z, c2v.w};
#pragma unroll
        for (int r = 0; r < 8; ++r) {
#pragma unroll
            for (int j = 0; j < 4; ++j) {
                // Replicate ref rounding: t = (x2 + c2) rounds, 2*dot exact,
                // then single-rounded subtract (== fmaf(-2,dot,t)).
                float t = x2v[r] + c2a[j];
                float f = fmaf(-2.0f, acc[r][j], t);
                f = fmaxf(f, 0.0f);
                float s = __builtin_sqrtf(f);            // correctly rounded
                unsigned long long key =
                    ((unsigned long long)__float_as_uint(s) << 32) |
                    (unsigned)(kk + j);
                if (key < best[r]) best[r] = key;        // tie -> lowest k
            }
        }
    }

    // Cross-lane min per row (u64 key butterfly), then gather + writes.
#pragma unroll
    for (int r = 0; r < 8; ++r) {
        unsigned long long b = best[r];
#pragma unroll
        for (int off = 32; off; off >>= 1) {
            unsigned long long o = __shfl_xor(b, off, 64);
            if (o < b) b = o;
        }
        int bk = (int)(b & 0xffffffffULL);
        // out[row] = center[bk]  (the STE forward value to <=1 ulp)
        float2 cv = ((const float2*)(center + (long)bk * ND))[lane];
        ((float2*)(out + (row_base + r) * ND))[lane] = cv;
        if (lane == 0) label_out[row_base + r] = (float)bk;
    }
}

// ---------------------------------------------------------------------------
extern "C" void kernel_launch(void* const* d_in, const int* in_sizes, int n_in,
                              void* d_out, int out_size, void* d_ws, size_t ws_size,
                              hipStream_t stream) {
    const float* x      = (const float*)d_in[0];   // [B][D]
    const float* center = (const float*)d_in[1];   // [K][D]
    float* out = (float*)d_out;

    float* out_x      = out;                        // [B*D]
    float* out_center = out + (long)NB * ND;        // [K*D]
    float* out_label  = out_center + (long)NK * ND; // [B]

    // Workspace layout (floats): cT[K*D], c2[K], x2[B]  (~1.07 MB)
    float* cT = (float*)d_ws;
    float* c2 = cT + (long)NK * ND;
    float* x2 = c2 + NK;

    transpose_center<<<(NK * ND) / 256, 256, 0, stream>>>(center, cT);
    compute_c2<<<NK / 256, 256, 0, stream>>>(center, c2);
    compute_x2<<<(NB * 64) / 256, 256, 0, stream>>>(x, x2);

    // center passthrough output
    hipMemcpyAsync(out_center, center, (size_t)NK * ND * sizeof(float),
                   hipMemcpyDeviceToDevice, stream);

    kmeans_main<<<NB / 32, 256, 0, stream>>>(x, center, cT, c2, x2,
                                             out_x, out_label);
}

// Round 2
// 186.858 us; speedup vs baseline: 1.1640x; 1.1640x over previous
//
#include <hip/hip_runtime.h>
#include <cstdint>

// B=16384 rows, K=2048 centers, D=128, T=1.0
// Outputs (flat, f32): out[B*D], center[K*D], label[B]
#define NB 16384
#define NK 2048
#define ND 128

// ---------------------------------------------------------------------------
// Fused prep: x2 + partial-init (blocks 0..4095), transpose (4096..5119),
// center passthrough copy (5120..5375), c2 (5376..5383).
// Arithmetic kept IDENTICAL to the round-1 passing kernel.
// ---------------------------------------------------------------------------
__global__ __launch_bounds__(256)
void prep(const float* __restrict__ x,
          const float* __restrict__ c,
          float* __restrict__ cT,
          float* __restrict__ c2,
          float* __restrict__ x2,
          float* __restrict__ out_center,
          unsigned long long* __restrict__ partial) {
    const int bid = blockIdx.x;
    const int tid = threadIdx.x;
    if (bid < 4096) {
        // x2: one wave per row, same butterfly order as round 1
        const int row  = bid * 4 + (tid >> 6);
        const int lane = tid & 63;
        float2 v = ((const float2*)(x + (long)row * ND))[lane];
        float s = v.x * v.x + v.y * v.y;
#pragma unroll
        for (int off = 32; off; off >>= 1) s += __shfl_xor(s, off, 64);
        if (lane == 0) {
            x2[row] = s;
            partial[row] = ~0ULL;            // init for atomicMin
        }
    } else if (bid < 5120) {
        // transpose center [K][D] -> cT [D][K]
        int t = (bid - 4096) * 256 + tid;    // 0 .. K*D-1
        int d = t >> 11;
        int k = t & (NK - 1);
        cT[t] = c[k * ND + d];
    } else if (bid < 5376) {
        // center passthrough, float4
        int i = (bid - 5120) * 256 + tid;    // 0 .. K*D/4-1
        ((float4*)out_center)[i] = ((const float4*)c)[i];
    } else {
        // c2[k], same expression/order as round 1
        int k = (bid - 5376) * 256 + tid;    // 0 .. K-1
        const float4* row = (const float4*)(c + (long)k * ND);
        float s = 0.f;
#pragma unroll 8
        for (int i = 0; i < ND / 4; ++i) {
            float4 v = row[i];
            s += v.x * v.x + v.y * v.y + v.z * v.z + v.w * v.w;
        }
        c2[k] = s;
    }
}

// ---------------------------------------------------------------------------
// Main: 1024 blocks x 512 threads. Block = 8 waves, all on the SAME k-quarter
// (shared cT stream -> L1 reuse); wave handles 8 rows; lane handles 4
// consecutive k per 256-k chunk (2 chunks per quarter).
// Per-row result combined across quarters via atomicMin on packed u64 key.
// ---------------------------------------------------------------------------
__global__ __launch_bounds__(512)
void kmeans_main(const float* __restrict__ x,
                 const float* __restrict__ cT,
                 const float* __restrict__ c2,
                 const float* __restrict__ x2,
                 unsigned long long* __restrict__ partial) {
    const int lane = threadIdx.x & 63;
    const int wave = __builtin_amdgcn_readfirstlane(threadIdx.x >> 6); // 0..7
    const int qa = blockIdx.x & 3;                  // k-quarter
    const int rg = blockIdx.x >> 2;                 // row-group of 64 rows
    const long row_base = (long)rg * 64 + wave * 8;
    const float* __restrict__ xr = x + row_base * ND;  // wave-uniform base

    float x2v[8];
#pragma unroll
    for (int r = 0; r < 8; ++r) x2v[r] = x2[row_base + r];  // uniform -> s_load

    float bestS[8];
    int   bestK[8];
#pragma unroll
    for (int r = 0; r < 8; ++r) { bestS[r] = __builtin_inff(); bestK[r] = 0; }

    for (int chunk = 0; chunk < 2; ++chunk) {
        const int kk = qa * 512 + chunk * 256 + lane * 4;  // lane's 4 k's
        float acc[8][4];
#pragma unroll
        for (int r = 0; r < 8; ++r)
#pragma unroll
            for (int j = 0; j < 4; ++j) acc[r][j] = 0.f;

        const float4* cptr = (const float4*)(cT + kk);     // row stride 512 f4
#pragma unroll 4
        for (int d = 0; d < ND; ++d) {
            float4 c4 = cptr[d * (NK / 4)];
#pragma unroll
            for (int r = 0; r < 8; ++r) {
                float xv = xr[r * ND + d];                 // uniform -> s_load
                acc[r][0] = fmaf(xv, c4.x, acc[r][0]);
                acc[r][1] = fmaf(xv, c4.y, acc[r][1]);
                acc[r][2] = fmaf(xv, c4.z, acc[r][2]);
                acc[r][3] = fmaf(xv, c4.w, acc[r][3]);
            }
        }

        float4 c2v = *(const float4*)(c2 + kk);
        float c2a[4] = {c2v.x, c2v.y, c2v.z, c2v.w};
#pragma unroll
        for (int r = 0; r < 8; ++r) {
#pragma unroll
            for (int j = 0; j < 4; ++j) {
                // Same fp32 chain as the exact-passing round-1 kernel.
                float t = x2v[r] + c2a[j];
                float f = fmaf(-2.0f, acc[r][j], t);
                f = fmaxf(f, 0.0f);
                float s = __builtin_sqrtf(f);
                // lane visits k strictly ascending -> strict < keeps lowest k
                if (s < bestS[r]) { bestS[r] = s; bestK[r] = kk + j; }
            }
        }
    }

    // Pack key once, wave-butterfly u64 min, one atomic per (row, quarter).
#pragma unroll
    for (int r = 0; r < 8; ++r) {
        unsigned long long b =
            ((unsigned long long)__float_as_uint(bestS[r]) << 32) |
            (unsigned)bestK[r];
#pragma unroll
        for (int off = 32; off; off >>= 1) {
            unsigned long long o = __shfl_xor(b, off, 64);
            if (o < b) b = o;
        }
        if (lane == 0) atomicMin(&partial[row_base + r], b);
    }
}

// ---------------------------------------------------------------------------
// Merge: one wave per row — read final key, gather center row, write label.
// ---------------------------------------------------------------------------
__global__ __launch_bounds__(256)
void merge(const unsigned long long* __restrict__ partial,
           const float* __restrict__ center,
           float* __restrict__ out,
           float* __restrict__ label_out) {
    const long row  = (long)blockIdx.x * 4 + (threadIdx.x >> 6);
    const int  lane = threadIdx.x & 63;
    unsigned long long b = partial[row];                 // uniform broadcast
    int bk = (int)(b & 0xffffffffULL);
    float2 cv = ((const float2*)(center + (long)bk * ND))[lane];
    ((float2*)(out + row * ND))[lane] = cv;
    if (lane == 0) label_out[row] = (float)bk;
}

// ---------------------------------------------------------------------------
extern "C" void kernel_launch(void* const* d_in, const int* in_sizes, int n_in,
                              void* d_out, int out_size, void* d_ws, size_t ws_size,
                              hipStream_t stream) {
    const float* x      = (const float*)d_in[0];   // [B][D]
    const float* center = (const float*)d_in[1];   // [K][D]
    float* out = (float*)d_out;

    float* out_x      = out;                        // [B*D]
    float* out_center = out + (long)NB * ND;        // [K*D]
    float* out_label  = out_center + (long)NK * ND; // [B]

    // Workspace: cT[K*D], c2[K], x2[B], partial[B] (u64)  (~1.25 MB)
    float* cT = (float*)d_ws;
    float* c2 = cT + (long)NK * ND;
    float* x2 = c2 + NK;
    unsigned long long* partial = (unsigned long long*)(x2 + NB);

    prep<<<5384, 256, 0, stream>>>(x, center, cT, c2, x2, out_center, partial);
    kmeans_main<<<1024, 512, 0, stream>>>(x, cT, c2, x2, partial);
    merge<<<NB / 4, 256, 0, stream>>>(partial, center, out_x, out_label);
}